// Round 19
// baseline (162.181 us; speedup 1.0000x reference)
//
#include <hip/hip_runtime.h>
#include <stdint.h>

#define MDIM 2048
#define KDIM 4096
#define NDIM 8192
#define NG   32            // K / GROUP_SIZE
#define QROW 2048          // int32 per qweight row
#define NT2  64            // K-tiles of BK=64
#define LSTR 36            // fused-fallback LDS row stride
#define BUFH 32768         // f16 per buffer: A[256][64] + B[256][64]

typedef __attribute__((ext_vector_type(4))) float    f32x4;
typedef __attribute__((ext_vector_type(2))) _Float16 f16x2;
typedef __attribute__((ext_vector_type(8))) _Float16 f16x8;
typedef __attribute__((ext_vector_type(4))) int      i32x4;

#define CVT2(a,b) __builtin_bit_cast(f16x2, __builtin_amdgcn_cvt_pkrtz((a),(b)))
#define BCU(x)    __builtin_bit_cast(unsigned, (x))
#define BCH2(x)   __builtin_bit_cast(f16x2, (x))
#define MFMA16(A,B,C) __builtin_amdgcn_mfma_f32_16x16x32_f16((A),(B),(C),0,0,0)
#define LDSREAD(DST, OFF) __builtin_memcpy(&(DST), &lds[(OFF)], 16)

__device__ __forceinline__ void gload_lds16(const void* g, void* l) {
  __builtin_amdgcn_global_load_lds(
      (const __attribute__((address_space(1))) void*)g,
      (__attribute__((address_space(3))) void*)l, 16, 0, 0);
}

// dequant 4 int32 (8 weights, identity k-order) -> 8 fp16 (verified r3..r18)
__device__ __forceinline__ uint4 dequant8(i32x4 q, float sf, float zf) {
  const _Float16 sh = (_Float16)sf;
  const _Float16 bh = (_Float16)(-zf * sf);
  const f16x2 s2 = {sh, sh}, b2 = {bh, bh};
  const f16x2 k2 = {(_Float16)1024.0f, (_Float16)1024.0f};
  uint4 r;
#define DQE(QV, DST) do {                                                   \
    unsigned Bb_ = (unsigned)(QV) & 0xFFu;                                  \
    unsigned bits_ = ((Bb_ | (Bb_ << 12)) & 0x000F000Fu) | 0x64006400u;     \
    DST = BCU((f16x2)((BCH2(bits_) - k2) * s2 + b2));                       \
  } while (0)
  DQE(q.x, r.x); DQE(q.y, r.y); DQE(q.z, r.z); DQE(q.w, r.w);
#undef DQE
  return r;
}

// ============ pass 1: A f32 -> f16 [M][K] in ws ============
__global__ __launch_bounds__(256) void conv_a_kernel(
    const float* __restrict__ A, _Float16* __restrict__ Af)
{
  const size_t total = (size_t)MDIM * (KDIM / 8);
  for (size_t t = (size_t)blockIdx.x * blockDim.x + threadIdx.x; t < total;
       t += (size_t)gridDim.x * blockDim.x) {
    f32x4 v0, v1;
    __builtin_memcpy(&v0, A + 8 * t,     16);
    __builtin_memcpy(&v1, A + 8 * t + 4, 16);
    uint4 h;
    h.x = BCU(CVT2(v0.x, v0.y));
    h.y = BCU(CVT2(v0.z, v0.w));
    h.z = BCU(CVT2(v1.x, v1.y));
    h.w = BCU(CVT2(v1.z, v1.w));
    __builtin_memcpy(Af + 8 * t, &h, 16);
  }
}

// ============ pass 2: f16 GEMM with INLINE W dequant ============
// r18 skeleton (verified PASS, GEMM 129.5us): 256x256, BK=64, 8 waves,
// 2 x 64KB bufs, A staged via gload_lds with pre-swizzled source, read
// chunk=(kk*4+h)^(fr&7) (0 conflicts), free-scheduled phases, 2 barriers/iter.
// NEW: W comes straight from packed qweight (no 128MB prepass round-trip).
// Per tile per thread: 6 vmem loads (4x dwordx4 qw + s + z) at iter top;
// dequant + 4 swizzled ds_write_b128 at P3 after counted vmcnt(4).
// Gate ledger (in-order vmem): top vmcnt(6) drains A(t) [leaves B(t+1)6];
// P3 vmcnt(4) drains B(t+1) [leaves A(t+1)4]; lgkmcnt(0)+clobber at P3 end
// retires ds_writes before next top barrier.
__global__ __launch_bounds__(512) void gemm_q_kernel(
    const _Float16* __restrict__ Af,   // [M][K] f16 (prepass)
    const int*      __restrict__ qw,   // [N][K/2] packed int32 (1 byte each)
    const float*    __restrict__ scales,
    const float*    __restrict__ zeros,
    const float*    __restrict__ bias,
    float*          __restrict__ out)  // [M][N] f32
{
  __shared__ __align__(16) _Float16 lds[2 * BUFH];   // 128 KB

  const int tid  = threadIdx.x;
  const int wave = tid >> 6;
  const int lane = tid & 63;
  const int n0 = blockIdx.x << 8;
  const int m0 = blockIdx.y << 8;
  const int wm = (wave >> 2) << 7;   // 0 or 128
  const int wn = (wave & 3) << 6;    // 0,64,128,192

  f32x4 acc[8][4] = {};

  // ---- A staging (r18 verbatim) ----
  const int srow   = tid >> 3;                      // 0..63
  const int schunk = (tid & 7) ^ ((tid >> 3) & 7);
  const _Float16* aU0 = Af + (size_t)(m0 + srow) * KDIM + schunk * 8;
  const _Float16* aU1 = aU0 + (size_t)64 * KDIM;
  const _Float16* aU2 = aU0 + (size_t)128 * KDIM;
  const _Float16* aU3 = aU0 + (size_t)192 * KDIM;

#define STAGE_A2a(X) do {                                              \
    _Float16* d_ = &lds[((X) & 1) * BUFH + (wave << 9)];               \
    const size_t ko_ = (size_t)(X) << 6;                               \
    gload_lds16(aU0 + ko_, d_);                                        \
    gload_lds16(aU1 + ko_, d_ + 4096);                                 \
  } while (0)
#define STAGE_A2b(X) do {                                              \
    _Float16* d_ = &lds[((X) & 1) * BUFH + (wave << 9)];               \
    const size_t ko_ = (size_t)(X) << 6;                               \
    gload_lds16(aU2 + ko_, d_ + 8192);                                 \
    gload_lds16(aU3 + ko_, d_ + 12288);                                \
  } while (0)

  // ---- B inline-dequant staging: thread handles row r, k-half kc ----
  const int brow = tid >> 1;          // 0..255 (N-row within tile)
  const int bkc  = tid & 1;           // 0 or 1 (32-k half of BK=64)
  const int bsw  = brow & 7;          // write-side swizzle key
  const int*   qB = qw + (size_t)(n0 + brow) * QROW + bkc * 16;
  const float* sB = scales + (size_t)(n0 + brow) * NG;
  const float* zB = zeros  + (size_t)(n0 + brow) * NG;

  i32x4 bq0, bq1, bq2, bq3;
  float bs, bz;

  // 6 vmem loads for tile X's B data (kept in regs until WRITE_B)
#define ISSUE_B(X) do {                                                \
    const int* q_ = qB + (size_t)(X) * 32;                             \
    __builtin_memcpy(&bq0, q_,      16);                               \
    __builtin_memcpy(&bq1, q_ + 4,  16);                               \
    __builtin_memcpy(&bq2, q_ + 8,  16);                               \
    __builtin_memcpy(&bq3, q_ + 12, 16);                               \
    const int g_ = (X) >> 1;                                           \
    __builtin_memcpy(&bs, sB + g_, 4);                                 \
    __builtin_memcpy(&bz, zB + g_, 4);                                 \
  } while (0)

  // dequant regs -> 4 swizzled ds_write_b128 into buf (X)&1 B region.
  // logical chunk 4*bkc+ci stored at chunk^(row&7)  (matches read swizzle;
  // 8 lanes per 4-bank group = 2-way = free)
#define WRITE_B(X) do {                                                \
    _Float16* db_ = &lds[((X) & 1) * BUFH + 16384 + brow * 64];        \
    uint4 w_;                                                          \
    w_ = dequant8(bq0, bs, bz);                                        \
    __builtin_memcpy(db_ + ((4 * bkc + 0) ^ bsw) * 8, &w_, 16);        \
    w_ = dequant8(bq1, bs, bz);                                        \
    __builtin_memcpy(db_ + ((4 * bkc + 1) ^ bsw) * 8, &w_, 16);        \
    w_ = dequant8(bq2, bs, bz);                                        \
    __builtin_memcpy(db_ + ((4 * bkc + 2) ^ bsw) * 8, &w_, 16);        \
    w_ = dequant8(bq3, bs, bz);                                        \
    __builtin_memcpy(db_ + ((4 * bkc + 3) ^ bsw) * 8, &w_, 16);        \
  } while (0)

  // ---- fragment read offsets (r14-r18 verbatim; measured 0 conflicts) ----
  const int fr = lane & 15;
  const int h4 = lane >> 4;
  const int ck0 = (((0 + h4) ^ (fr & 7))) << 3;
  const int ck1 = (((4 + h4) ^ (fr & 7))) << 3;
  int raOff[8], rbOff[4];
#pragma unroll
  for (int i = 0; i < 8; ++i) raOff[i] = (wm + 16 * i + fr) * 64;
#pragma unroll
  for (int j = 0; j < 4; ++j) rbOff[j] = 16384 + (wn + 16 * j + fr) * 64;

  // tail compute (r14-r18 verbatim, no staging)
#define COMPUTE(T) do {                                                \
    const int bb_ = ((T) & 1) * BUFH;                                  \
    f16x8 b0_[4], b1_[4];                                              \
    _Pragma("unroll")                                                  \
    for (int j = 0; j < 4; ++j) {                                      \
      LDSREAD(b0_[j], bb_ + rbOff[j] + ck0);                           \
      LDSREAD(b1_[j], bb_ + rbOff[j] + ck1);                           \
    }                                                                  \
    _Pragma("unroll")                                                  \
    for (int i = 0; i < 8; ++i) {                                      \
      f16x8 a0_, a1_;                                                  \
      LDSREAD(a0_, bb_ + raOff[i] + ck0);                              \
      LDSREAD(a1_, bb_ + raOff[i] + ck1);                              \
      _Pragma("unroll")                                                \
      for (int j = 0; j < 4; ++j)                                      \
        acc[i][j] = MFMA16(a0_, b0_[j], acc[i][j]);                    \
      _Pragma("unroll")                                                \
      for (int j = 0; j < 4; ++j)                                      \
        acc[i][j] = MFMA16(a1_, b1_[j], acc[i][j]);                    \
    }                                                                  \
  } while (0)

  // 16-MFMA phase body (r14-r18 verbatim)
#define PH_MFMA(R) do {                                                \
    __builtin_amdgcn_s_setprio(1);                                     \
    _Pragma("unroll")                                                  \
    for (int j = 0; j < 4; ++j) {                                      \
      acc[(R)][j]     = MFMA16(aA0, bf0[j], acc[(R)][j]);              \
      acc[(R) + 1][j] = MFMA16(aB0, bf0[j], acc[(R) + 1][j]);          \
    }                                                                  \
    _Pragma("unroll")                                                  \
    for (int j = 0; j < 4; ++j) {                                      \
      acc[(R)][j]     = MFMA16(aA1, bf1[j], acc[(R)][j]);              \
      acc[(R) + 1][j] = MFMA16(aB1, bf1[j], acc[(R) + 1][j]);          \
    }                                                                  \
    __builtin_amdgcn_s_setprio(0);                                     \
  } while (0)

#define RD_A(I)                                                        \
    LDSREAD(aA0, bb + raOff[I] + ck0);                                 \
    LDSREAD(aA1, bb + raOff[I] + ck1);                                 \
    LDSREAD(aB0, bb + raOff[(I) + 1] + ck0);                           \
    LDSREAD(aB1, bb + raOff[(I) + 1] + ck1);

  // ---- prologue: tile 0 (B via regs+write, A via gload) ----
  ISSUE_B(0);                                       // 6 vmem
  STAGE_A2a(0); STAGE_A2b(0);                       // 4 gload_lds
  asm volatile("s_waitcnt vmcnt(4)" ::: "memory");  // B(0) regs ready
  WRITE_B(0);
  asm volatile("s_waitcnt lgkmcnt(0)" ::: "memory");

#pragma clang loop unroll(disable)
  for (int t = 0; t < NT2 - 1; ++t) {
    ISSUE_B(t + 1);                                   // outstanding: A(t)4 + B(t+1)6
    asm volatile("s_waitcnt vmcnt(6)" ::: "memory");  // A(t) landed
    __builtin_amdgcn_s_barrier();                     // tile t fully visible
    const int bb = (t & 1) * BUFH;

    f16x8 bf0[4], bf1[4], aA0, aA1, aB0, aB1;

    // ---- P0: all B frags + A rows 0,1 | A(t+1) gloads 1,2 ----
#pragma unroll
    for (int j = 0; j < 4; ++j) {
      LDSREAD(bf0[j], bb + rbOff[j] + ck0);
      LDSREAD(bf1[j], bb + rbOff[j] + ck1);
    }
    RD_A(0)
    STAGE_A2a(t + 1);
    PH_MFMA(0);

    // ---- P1: A rows 2,3 | A(t+1) gloads 3,4 ----
    RD_A(2)
    STAGE_A2b(t + 1);
    PH_MFMA(2);

    // ---- P2: A rows 4,5 ----
    RD_A(4)
    PH_MFMA(4);

    // ---- P3: A rows 6,7 | B(t+1) dequant + ds_write | MFMA ----
    RD_A(6)
    asm volatile("s_waitcnt vmcnt(4)" ::: "memory");  // B(t+1) regs landed
    WRITE_B(t + 1);                                   // into buf (t+1)&1
    PH_MFMA(6);
    asm volatile("s_waitcnt lgkmcnt(0)" ::: "memory"); // ds_writes retired
  }

  // tail: tile NT2-1 (A staged in iter NT2-2 P0/P1; B written at its P3)
  asm volatile("s_waitcnt vmcnt(0)" ::: "memory");
  __builtin_amdgcn_s_barrier();
  COMPUTE(NT2 - 1);

#undef STAGE_A2a
#undef STAGE_A2b
#undef ISSUE_B
#undef WRITE_B
#undef COMPUTE
#undef PH_MFMA
#undef RD_A

  // epilogue: C/D col = lane&15, row = (lane>>4)*4 + reg (r9-r18 verbatim)
  const int cr = (lane >> 4) << 2;
  const int cc = lane & 15;
#pragma unroll
  for (int j = 0; j < 4; ++j) {
    const int n = n0 + wn + j * 16 + cc;
    const float bv = bias[n];
#pragma unroll
    for (int i = 0; i < 8; ++i) {
      const int mrow = m0 + wm + i * 16 + cr;
#pragma unroll
      for (int r = 0; r < 4; ++r)
        out[(size_t)(mrow + r) * NDIM + n] = acc[i][j][r] + bv;
    }
  }
}

// ============ fused fallback (round-6 kernel, verified PASS) ============
__global__ __launch_bounds__(256, 4) void qlin_fused_kernel(
    const float* __restrict__ A, const int* __restrict__ qw,
    const float* __restrict__ scales, const float* __restrict__ zeros,
    const float* __restrict__ bias, float* __restrict__ out)
{
  __shared__ _Float16 As[2][128 * LSTR];
  __shared__ _Float16 Bs[2][128 * LSTR];

  const int tid  = threadIdx.x;
  const int wave = tid >> 6;
  const int lane = tid & 63;
  const int n0 = blockIdx.x << 7;
  const int m0 = blockIdx.y << 7;
  const int wm = (wave >> 1) << 6;
  const int wn = (wave & 1) << 6;

  f32x4 acc[4][4] = {};

  const int r4 = tid >> 2;
  const int c4 = tid & 3;

  const float* aP0 = A + (size_t)(m0 + r4) * KDIM + c4 * 8;
  const float* aP1 = aP0 + (size_t)64 * KDIM;
  const int*   qP0 = qw + (size_t)(n0 + r4) * QROW + c4 * 4;
  const int*   qP1 = qP0 + (size_t)64 * QROW;
  const float* sP0 = scales + (size_t)(n0 + r4) * NG;
  const float* zP0 = zeros  + (size_t)(n0 + r4) * NG;
  const float* sP1 = sP0 + (size_t)64 * NG;
  const float* zP1 = zP0 + (size_t)64 * NG;

  const int aD0 = r4 * LSTR + c4 * 8;
  const int aD1 = (r4 + 64) * LSTR + c4 * 8;

  const int fr = lane & 15;
  const int k0 = (lane >> 4) * 8;
  const int ra0 = (wm +  0 + fr) * LSTR + k0;
  const int ra1 = (wm + 16 + fr) * LSTR + k0;
  const int ra2 = (wm + 32 + fr) * LSTR + k0;
  const int ra3 = (wm + 48 + fr) * LSTR + k0;
  const int rb0 = (wn +  0 + fr) * LSTR + k0;
  const int rb1 = (wn + 16 + fr) * LSTR + k0;
  const int rb2 = (wn + 32 + fr) * LSTR + k0;
  const int rb3 = (wn + 48 + fr) * LSTR + k0;

  f32x4 pa0, pa1, pa2, pa3;
  i32x4 pq0, pq1;
  float psf0, pzf0, psf1, pzf1;

#define ISSUE(KT) do {                                                        \
    __builtin_memcpy(&pa0, aP0 + (size_t)(KT) * 32,     16);                  \
    __builtin_memcpy(&pa1, aP0 + (size_t)(KT) * 32 + 4, 16);                  \
    __builtin_memcpy(&pa2, aP1 + (size_t)(KT) * 32,     16);                  \
    __builtin_memcpy(&pa3, aP1 + (size_t)(KT) * 32 + 4, 16);                  \
    __builtin_memcpy(&pq0, qP0 + (size_t)(KT) * 16, 16);                      \
    __builtin_memcpy(&pq1, qP1 + (size_t)(KT) * 16, 16);                      \
    const int g_ = (KT) >> 2;                                                 \
    psf0 = sP0[g_]; pzf0 = zP0[g_];                                           \
    psf1 = sP1[g_]; pzf1 = zP1[g_];                                           \
  } while (0)

#define STAGE(P) do {                                                         \
    uint4 aw0_;                                                               \
    aw0_.x = BCU(CVT2(pa0.x, pa0.y));                                         \
    aw0_.y = BCU(CVT2(pa0.z, pa0.w));                                         \
    aw0_.z = BCU(CVT2(pa1.x, pa1.y));                                         \
    aw0_.w = BCU(CVT2(pa1.z, pa1.w));                                         \
    __builtin_memcpy(&As[P][aD0], &aw0_, 16);                                 \
    uint4 aw1_;                                                               \
    aw1_.x = BCU(CVT2(pa2.x, pa2.y));                                         \
    aw1_.y = BCU(CVT2(pa2.z, pa2.w));                                         \
    aw1_.z = BCU(CVT2(pa3.x, pa3.y));                                         \
    aw1_.w = BCU(CVT2(pa3.z, pa3.w));                                         \
    __builtin_memcpy(&As[P][aD1], &aw1_, 16);                                 \
    uint4 bw0_ = dequant8(pq0, psf0, pzf0);                                   \
    __builtin_memcpy(&Bs[P][aD0], &bw0_, 16);                                 \
    uint4 bw1_ = dequant8(pq1, psf1, pzf1);                                   \
    __builtin_memcpy(&Bs[P][aD1], &bw1_, 16);                                 \
  } while (0)

#define COMPUTE(P) do {                                                       \
    f16x8 af[4], bfr[4];                                                      \
    __builtin_memcpy(&af[0], &As[P][ra0], 16);                                \
    __builtin_memcpy(&af[1], &As[P][ra1], 16);                                \
    __builtin_memcpy(&af[2], &As[P][ra2], 16);                                \
    __builtin_memcpy(&af[3], &As[P][ra3], 16);                                \
    __builtin_memcpy(&bfr[0], &Bs[P][rb0], 16);                               \
    __builtin_memcpy(&bfr[1], &Bs[P][rb1], 16);                               \
    __builtin_memcpy(&bfr[2], &Bs[P][rb2], 16);                               \
    __builtin_memcpy(&bfr[3], &Bs[P][rb3], 16);                               \
    _Pragma("unroll")                                                         \
    for (int i = 0; i < 4; ++i)                                               \
      _Pragma("unroll")                                                       \
      for (int j = 0; j < 4; ++j)                                             \
        acc[i][j] = MFMA16(af[i], bfr[j], acc[i][j]);                         \
  } while (0)

  ISSUE(0);
  STAGE(0);
  __syncthreads();

#pragma clang loop unroll(disable)
  for (int kt = 0; kt < 127; ++kt) {
    const int p = kt & 1;
    ISSUE(kt + 1);
    COMPUTE(p);
    STAGE(p ^ 1);
    __syncthreads();
  }
  COMPUTE(1);

#undef ISSUE
#undef STAGE
#undef COMPUTE

  const int cr = (lane >> 4) << 2;
  const int cc = lane & 15;
#pragma unroll
  for (int j = 0; j < 4; ++j) {
    const int n = n0 + wn + j * 16 + cc;
    const float bv = bias[n];
#pragma unroll
    for (int i = 0; i < 4; ++i) {
      const int mrow = m0 + wm + i * 16 + cr;
#pragma unroll
      for (int r = 0; r < 4; ++r)
        out[(size_t)(mrow + r) * NDIM + n] = acc[i][j][r] + bv;
    }
  }
}

extern "C" void kernel_launch(void* const* d_in, const int* in_sizes, int n_in,
                              void* d_out, int out_size, void* d_ws, size_t ws_size,
                              hipStream_t stream) {
  const float* A      = (const float*)d_in[0];
  const int*   qwp    = (const int*)d_in[1];
  const float* scales = (const float*)d_in[2];
  const float* zerosp = (const float*)d_in[3];
  const float* biasp  = (const float*)d_in[4];
  float*       outp   = (float*)d_out;

  const size_t needA = (size_t)MDIM * KDIM * sizeof(_Float16);   // 16 MB

  if (ws_size >= needA) {
    _Float16* Af = (_Float16*)d_ws;
    conv_a_kernel<<<2048, 256, 0, stream>>>(A, Af);
    dim3 grid(NDIM / 256, MDIM / 256);  // 32 x 8 = 256 blocks (1/CU)
    gemm_q_kernel<<<grid, 512, 0, stream>>>(Af, qwp, scales, zerosp, biasp, outp);
  } else {
    dim3 grid(NDIM / 128, MDIM / 128);
    qlin_fused_kernel<<<grid, 256, 0, stream>>>(A, qwp, scales, zerosp, biasp, outp);
  }
}

// Round 20
// 153.958 us; speedup vs baseline: 1.0534x; 1.0534x over previous
//
#include <hip/hip_runtime.h>
#include <stdint.h>

#define MDIM 2048
#define KDIM 4096
#define NDIM 8192
#define NG   32            // K / GROUP_SIZE
#define QROW 2048          // int32 per qweight row
#define NT2  64            // K-tiles of BK=64
#define LSTR 36            // fused-fallback LDS row stride
#define BUFH 32768         // f16 per buffer: A[256][64] + B[256][64]

typedef __attribute__((ext_vector_type(4))) float    f32x4;
typedef __attribute__((ext_vector_type(2))) _Float16 f16x2;
typedef __attribute__((ext_vector_type(8))) _Float16 f16x8;
typedef __attribute__((ext_vector_type(4))) int      i32x4;

#define CVT2(a,b) __builtin_bit_cast(f16x2, __builtin_amdgcn_cvt_pkrtz((a),(b)))
#define BCU(x)    __builtin_bit_cast(unsigned, (x))
#define BCH2(x)   __builtin_bit_cast(f16x2, (x))
#define MFMA16(A,B,C) __builtin_amdgcn_mfma_f32_16x16x32_f16((A),(B),(C),0,0,0)
#define LDSREAD(DST, OFF) __builtin_memcpy(&(DST), &lds[(OFF)], 16)

__device__ __forceinline__ void gload_lds16(const void* g, void* l) {
  __builtin_amdgcn_global_load_lds(
      (const __attribute__((address_space(1))) void*)g,
      (__attribute__((address_space(3))) void*)l, 16, 0, 0);
}

// dequant 4 int32 (8 weights, identity k-order) -> 8 fp16 (verified r3..r19)
__device__ __forceinline__ uint4 dequant8(i32x4 q, float sf, float zf) {
  const _Float16 sh = (_Float16)sf;
  const _Float16 bh = (_Float16)(-zf * sf);
  const f16x2 s2 = {sh, sh}, b2 = {bh, bh};
  const f16x2 k2 = {(_Float16)1024.0f, (_Float16)1024.0f};
  uint4 r;
#define DQE(QV, DST) do {                                                   \
    unsigned Bb_ = (unsigned)(QV) & 0xFFu;                                  \
    unsigned bits_ = ((Bb_ | (Bb_ << 12)) & 0x000F000Fu) | 0x64006400u;     \
    DST = BCU((f16x2)((BCH2(bits_) - k2) * s2 + b2));                       \
  } while (0)
  DQE(q.x, r.x); DQE(q.y, r.y); DQE(q.z, r.z); DQE(q.w, r.w);
#undef DQE
  return r;
}

// ============ pass 1: A f32 -> f16 [M][K] in ws ============
__global__ __launch_bounds__(256) void conv_a_kernel(
    const float* __restrict__ A, _Float16* __restrict__ Af)
{
  const size_t total = (size_t)MDIM * (KDIM / 8);
  for (size_t t = (size_t)blockIdx.x * blockDim.x + threadIdx.x; t < total;
       t += (size_t)gridDim.x * blockDim.x) {
    f32x4 v0, v1;
    __builtin_memcpy(&v0, A + 8 * t,     16);
    __builtin_memcpy(&v1, A + 8 * t + 4, 16);
    uint4 h;
    h.x = BCU(CVT2(v0.x, v0.y));
    h.y = BCU(CVT2(v0.z, v0.w));
    h.z = BCU(CVT2(v1.x, v1.y));
    h.w = BCU(CVT2(v1.z, v1.w));
    __builtin_memcpy(Af + 8 * t, &h, 16);
  }
}

// ============ pass 2: f16 GEMM with INLINE W dequant (coalescing-fixed) ============
// r18 skeleton (verified): 256x256, BK=64, 8 waves, 2 x 64KB bufs, A via
// gload_lds pre-swizzled source, read chunk=(kk*4+h)^(fr&7) (0 conflicts),
// free-scheduled phases, 2 barriers/iter.
// B inline-dequant, COALESCED (fix of r19's regression): thread handles
// rows (tid>>3)+64i (i=0..3) at chunk tid&7 -> each load instruction: 8-lane
// groups read 128B contiguous per row (same transaction shape as A staging).
// Ledger: ISSUE_B = 12 vmem (4 qw + 4 s + 4 z); top gate vmcnt(12) drains
// A(t); P3 vmcnt(4) drains B(t+1) leaving A(t+1); lgkmcnt(0) at iter end.
__global__ __launch_bounds__(512) void gemm_q_kernel(
    const _Float16* __restrict__ Af,   // [M][K] f16 (prepass)
    const int*      __restrict__ qw,   // [N][K/2] packed int32 (1 byte each)
    const float*    __restrict__ scales,
    const float*    __restrict__ zeros,
    const float*    __restrict__ bias,
    float*          __restrict__ out)  // [M][N] f32
{
  __shared__ __align__(16) _Float16 lds[2 * BUFH];   // 128 KB

  const int tid  = threadIdx.x;
  const int wave = tid >> 6;
  const int lane = tid & 63;
  const int n0 = blockIdx.x << 8;
  const int m0 = blockIdx.y << 8;
  const int wm = (wave >> 2) << 7;   // 0 or 128
  const int wn = (wave & 3) << 6;    // 0,64,128,192

  f32x4 acc[8][4] = {};

  // ---- A staging (r18 verbatim) ----
  const int srow   = tid >> 3;                      // 0..63
  const int schunk = (tid & 7) ^ ((tid >> 3) & 7);
  const _Float16* aU0 = Af + (size_t)(m0 + srow) * KDIM + schunk * 8;
  const _Float16* aU1 = aU0 + (size_t)64 * KDIM;
  const _Float16* aU2 = aU0 + (size_t)128 * KDIM;
  const _Float16* aU3 = aU0 + (size_t)192 * KDIM;

#define STAGE_A2a(X) do {                                              \
    _Float16* d_ = &lds[((X) & 1) * BUFH + (wave << 9)];               \
    const size_t ko_ = (size_t)(X) << 6;                               \
    gload_lds16(aU0 + ko_, d_);                                        \
    gload_lds16(aU1 + ko_, d_ + 4096);                                 \
  } while (0)
#define STAGE_A2b(X) do {                                              \
    _Float16* d_ = &lds[((X) & 1) * BUFH + (wave << 9)];               \
    const size_t ko_ = (size_t)(X) << 6;                               \
    gload_lds16(aU2 + ko_, d_ + 8192);                                 \
    gload_lds16(aU3 + ko_, d_ + 12288);                                \
  } while (0)

  // ---- B inline-dequant staging (coalesced) ----
  // thread: rows br0..br3 = (tid>>3)+{0,64,128,192}, chunk j = tid&7.
  // Per load instruction: 8 lanes x 16B = 128B contiguous per row.
  const int br0 = tid >> 3;           // 0..63
  const int bj  = tid & 7;            // 16B chunk within row's 128B tile slice
  const int bsw = br0 & 7;            // swizzle key (same for all 4 rows: +64i == 0 mod 8)
  const int*   qB0 = qw + (size_t)(n0 + br0) * QROW + bj * 4;
  const int*   qB1 = qB0 + (size_t)64 * QROW;
  const int*   qB2 = qB0 + (size_t)128 * QROW;
  const int*   qB3 = qB0 + (size_t)192 * QROW;
  const float* sB0 = scales + (size_t)(n0 + br0) * NG;
  const float* sB1 = sB0 + (size_t)64 * NG;
  const float* sB2 = sB0 + (size_t)128 * NG;
  const float* sB3 = sB0 + (size_t)192 * NG;
  const float* zB0 = zeros + (size_t)(n0 + br0) * NG;
  const float* zB1 = zB0 + (size_t)64 * NG;
  const float* zB2 = zB0 + (size_t)128 * NG;
  const float* zB3 = zB0 + (size_t)192 * NG;

  i32x4 bq0, bq1, bq2, bq3;
  float bs0, bs1, bs2, bs3, bz0, bz1, bz2, bz3;

  // 12 vmem loads for tile X's B data (kept in regs until WRITE_B)
#define ISSUE_B(X) do {                                                \
    const size_t qo_ = (size_t)(X) * 32;                               \
    __builtin_memcpy(&bq0, qB0 + qo_, 16);                             \
    __builtin_memcpy(&bq1, qB1 + qo_, 16);                             \
    __builtin_memcpy(&bq2, qB2 + qo_, 16);                             \
    __builtin_memcpy(&bq3, qB3 + qo_, 16);                             \
    const int g_ = (X) >> 1;                                           \
    __builtin_memcpy(&bs0, sB0 + g_, 4);                               \
    __builtin_memcpy(&bs1, sB1 + g_, 4);                               \
    __builtin_memcpy(&bs2, sB2 + g_, 4);                               \
    __builtin_memcpy(&bs3, sB3 + g_, 4);                               \
    __builtin_memcpy(&bz0, zB0 + g_, 4);                               \
    __builtin_memcpy(&bz1, zB1 + g_, 4);                               \
    __builtin_memcpy(&bz2, zB2 + g_, 4);                               \
    __builtin_memcpy(&bz3, zB3 + g_, 4);                               \
  } while (0)

  // dequant regs -> 4 swizzled ds_write_b128 into buf (X)&1 B region.
  // logical chunk bj stored at bj^(row&7); per 8-lane group the 8 chunks are
  // a permutation of the row's full 128B -> 2-way banks = free.
#define WRITE_B(X) do {                                                \
    _Float16* db_ = &lds[((X) & 1) * BUFH + 16384];                    \
    const int sc_ = (bj ^ bsw) * 8;                                    \
    uint4 w_;                                                          \
    w_ = dequant8(bq0, bs0, bz0);                                      \
    __builtin_memcpy(db_ + (br0      ) * 64 + sc_, &w_, 16);           \
    w_ = dequant8(bq1, bs1, bz1);                                      \
    __builtin_memcpy(db_ + (br0 +  64) * 64 + sc_, &w_, 16);           \
    w_ = dequant8(bq2, bs2, bz2);                                      \
    __builtin_memcpy(db_ + (br0 + 128) * 64 + sc_, &w_, 16);           \
    w_ = dequant8(bq3, bs3, bz3);                                      \
    __builtin_memcpy(db_ + (br0 + 192) * 64 + sc_, &w_, 16);           \
  } while (0)

  // ---- fragment read offsets (r14-r18 verbatim; measured 0 conflicts) ----
  const int fr = lane & 15;
  const int h4 = lane >> 4;
  const int ck0 = (((0 + h4) ^ (fr & 7))) << 3;
  const int ck1 = (((4 + h4) ^ (fr & 7))) << 3;
  int raOff[8], rbOff[4];
#pragma unroll
  for (int i = 0; i < 8; ++i) raOff[i] = (wm + 16 * i + fr) * 64;
#pragma unroll
  for (int j = 0; j < 4; ++j) rbOff[j] = 16384 + (wn + 16 * j + fr) * 64;

  // tail compute (r14-r18 verbatim, no staging)
#define COMPUTE(T) do {                                                \
    const int bb_ = ((T) & 1) * BUFH;                                  \
    f16x8 b0_[4], b1_[4];                                              \
    _Pragma("unroll")                                                  \
    for (int j = 0; j < 4; ++j) {                                      \
      LDSREAD(b0_[j], bb_ + rbOff[j] + ck0);                           \
      LDSREAD(b1_[j], bb_ + rbOff[j] + ck1);                           \
    }                                                                  \
    _Pragma("unroll")                                                  \
    for (int i = 0; i < 8; ++i) {                                      \
      f16x8 a0_, a1_;                                                  \
      LDSREAD(a0_, bb_ + raOff[i] + ck0);                              \
      LDSREAD(a1_, bb_ + raOff[i] + ck1);                              \
      _Pragma("unroll")                                                \
      for (int j = 0; j < 4; ++j)                                      \
        acc[i][j] = MFMA16(a0_, b0_[j], acc[i][j]);                    \
      _Pragma("unroll")                                                \
      for (int j = 0; j < 4; ++j)                                      \
        acc[i][j] = MFMA16(a1_, b1_[j], acc[i][j]);                    \
    }                                                                  \
  } while (0)

  // 16-MFMA phase body (r14-r18 verbatim)
#define PH_MFMA(R) do {                                                \
    __builtin_amdgcn_s_setprio(1);                                     \
    _Pragma("unroll")                                                  \
    for (int j = 0; j < 4; ++j) {                                      \
      acc[(R)][j]     = MFMA16(aA0, bf0[j], acc[(R)][j]);              \
      acc[(R) + 1][j] = MFMA16(aB0, bf0[j], acc[(R) + 1][j]);          \
    }                                                                  \
    _Pragma("unroll")                                                  \
    for (int j = 0; j < 4; ++j) {                                      \
      acc[(R)][j]     = MFMA16(aA1, bf1[j], acc[(R)][j]);              \
      acc[(R) + 1][j] = MFMA16(aB1, bf1[j], acc[(R) + 1][j]);          \
    }                                                                  \
    __builtin_amdgcn_s_setprio(0);                                     \
  } while (0)

#define RD_A(I)                                                        \
    LDSREAD(aA0, bb + raOff[I] + ck0);                                 \
    LDSREAD(aA1, bb + raOff[I] + ck1);                                 \
    LDSREAD(aB0, bb + raOff[(I) + 1] + ck0);                           \
    LDSREAD(aB1, bb + raOff[(I) + 1] + ck1);

  // ---- prologue: tile 0 ----
  ISSUE_B(0);                                       // 12 vmem
  STAGE_A2a(0); STAGE_A2b(0);                       // 4 gload_lds
  asm volatile("s_waitcnt vmcnt(4)" ::: "memory");  // B(0) regs ready (A(0) in flight)
  WRITE_B(0);
  asm volatile("s_waitcnt lgkmcnt(0)" ::: "memory");

#pragma clang loop unroll(disable)
  for (int t = 0; t < NT2 - 1; ++t) {
    ISSUE_B(t + 1);                                   // outstanding: A(t)4 + B(t+1)12
    asm volatile("s_waitcnt vmcnt(12)" ::: "memory"); // A(t) landed
    __builtin_amdgcn_s_barrier();                     // tile t fully visible
    const int bb = (t & 1) * BUFH;

    f16x8 bf0[4], bf1[4], aA0, aA1, aB0, aB1;

    // ---- P0: all B frags + A rows 0,1 | A(t+1) gloads 1,2 ----
#pragma unroll
    for (int j = 0; j < 4; ++j) {
      LDSREAD(bf0[j], bb + rbOff[j] + ck0);
      LDSREAD(bf1[j], bb + rbOff[j] + ck1);
    }
    RD_A(0)
    STAGE_A2a(t + 1);
    PH_MFMA(0);

    // ---- P1: A rows 2,3 | A(t+1) gloads 3,4 ----
    RD_A(2)
    STAGE_A2b(t + 1);
    PH_MFMA(2);

    // ---- P2: A rows 4,5 ----
    RD_A(4)
    PH_MFMA(4);

    // ---- P3: A rows 6,7 | B(t+1) dequant + ds_write | MFMA ----
    RD_A(6)
    asm volatile("s_waitcnt vmcnt(4)" ::: "memory");  // B(t+1) regs landed
    WRITE_B(t + 1);                                   // into buf (t+1)&1
    PH_MFMA(6);
    asm volatile("s_waitcnt lgkmcnt(0)" ::: "memory"); // ds_writes retired
  }

  // tail: tile NT2-1 (A staged in iter NT2-2 P0/P1; B written at its P3)
  asm volatile("s_waitcnt vmcnt(0)" ::: "memory");
  __builtin_amdgcn_s_barrier();
  COMPUTE(NT2 - 1);

#undef STAGE_A2a
#undef STAGE_A2b
#undef ISSUE_B
#undef WRITE_B
#undef COMPUTE
#undef PH_MFMA
#undef RD_A

  // epilogue: C/D col = lane&15, row = (lane>>4)*4 + reg (r9-r18 verbatim)
  const int cr = (lane >> 4) << 2;
  const int cc = lane & 15;
#pragma unroll
  for (int j = 0; j < 4; ++j) {
    const int n = n0 + wn + j * 16 + cc;
    const float bv = bias[n];
#pragma unroll
    for (int i = 0; i < 8; ++i) {
      const int mrow = m0 + wm + i * 16 + cr;
#pragma unroll
      for (int r = 0; r < 4; ++r)
        out[(size_t)(mrow + r) * NDIM + n] = acc[i][j][r] + bv;
    }
  }
}

// ============ fused fallback (round-6 kernel, verified PASS) ============
__global__ __launch_bounds__(256, 4) void qlin_fused_kernel(
    const float* __restrict__ A, const int* __restrict__ qw,
    const float* __restrict__ scales, const float* __restrict__ zeros,
    const float* __restrict__ bias, float* __restrict__ out)
{
  __shared__ _Float16 As[2][128 * LSTR];
  __shared__ _Float16 Bs[2][128 * LSTR];

  const int tid  = threadIdx.x;
  const int wave = tid >> 6;
  const int lane = tid & 63;
  const int n0 = blockIdx.x << 7;
  const int m0 = blockIdx.y << 7;
  const int wm = (wave >> 1) << 6;
  const int wn = (wave & 1) << 6;

  f32x4 acc[4][4] = {};

  const int r4 = tid >> 2;
  const int c4 = tid & 3;

  const float* aP0 = A + (size_t)(m0 + r4) * KDIM + c4 * 8;
  const float* aP1 = aP0 + (size_t)64 * KDIM;
  const int*   qP0 = qw + (size_t)(n0 + r4) * QROW + c4 * 4;
  const int*   qP1 = qP0 + (size_t)64 * QROW;
  const float* sP0 = scales + (size_t)(n0 + r4) * NG;
  const float* zP0 = zeros  + (size_t)(n0 + r4) * NG;
  const float* sP1 = sP0 + (size_t)64 * NG;
  const float* zP1 = zP0 + (size_t)64 * NG;

  const int aD0 = r4 * LSTR + c4 * 8;
  const int aD1 = (r4 + 64) * LSTR + c4 * 8;

  const int fr = lane & 15;
  const int k0 = (lane >> 4) * 8;
  const int ra0 = (wm +  0 + fr) * LSTR + k0;
  const int ra1 = (wm + 16 + fr) * LSTR + k0;
  const int ra2 = (wm + 32 + fr) * LSTR + k0;
  const int ra3 = (wm + 48 + fr) * LSTR + k0;
  const int rb0 = (wn +  0 + fr) * LSTR + k0;
  const int rb1 = (wn + 16 + fr) * LSTR + k0;
  const int rb2 = (wn + 32 + fr) * LSTR + k0;
  const int rb3 = (wn + 48 + fr) * LSTR + k0;

  f32x4 pa0, pa1, pa2, pa3;
  i32x4 pq0, pq1;
  float psf0, pzf0, psf1, pzf1;

#define ISSUE(KT) do {                                                        \
    __builtin_memcpy(&pa0, aP0 + (size_t)(KT) * 32,     16);                  \
    __builtin_memcpy(&pa1, aP0 + (size_t)(KT) * 32 + 4, 16);                  \
    __builtin_memcpy(&pa2, aP1 + (size_t)(KT) * 32,     16);                  \
    __builtin_memcpy(&pa3, aP1 + (size_t)(KT) * 32 + 4, 16);                  \
    __builtin_memcpy(&pq0, qP0 + (size_t)(KT) * 16, 16);                      \
    __builtin_memcpy(&pq1, qP1 + (size_t)(KT) * 16, 16);                      \
    const int g_ = (KT) >> 2;                                                 \
    psf0 = sP0[g_]; pzf0 = zP0[g_];                                           \
    psf1 = sP1[g_]; pzf1 = zP1[g_];                                           \
  } while (0)

#define STAGE(P) do {                                                         \
    uint4 aw0_;                                                               \
    aw0_.x = BCU(CVT2(pa0.x, pa0.y));                                         \
    aw0_.y = BCU(CVT2(pa0.z, pa0.w));                                         \
    aw0_.z = BCU(CVT2(pa1.x, pa1.y));                                         \
    aw0_.w = BCU(CVT2(pa1.z, pa1.w));                                         \
    __builtin_memcpy(&As[P][aD0], &aw0_, 16);                                 \
    uint4 aw1_;                                                               \
    aw1_.x = BCU(CVT2(pa2.x, pa2.y));                                         \
    aw1_.y = BCU(CVT2(pa2.z, pa2.w));                                         \
    aw1_.z = BCU(CVT2(pa3.x, pa3.y));                                         \
    aw1_.w = BCU(CVT2(pa3.z, pa3.w));                                         \
    __builtin_memcpy(&As[P][aD1], &aw1_, 16);                                 \
    uint4 bw0_ = dequant8(pq0, psf0, pzf0);                                   \
    __builtin_memcpy(&Bs[P][aD0], &bw0_, 16);                                 \
    uint4 bw1_ = dequant8(pq1, psf1, pzf1);                                   \
    __builtin_memcpy(&Bs[P][aD1], &bw1_, 16);                                 \
  } while (0)

#define COMPUTE(P) do {                                                       \
    f16x8 af[4], bfr[4];                                                      \
    __builtin_memcpy(&af[0], &As[P][ra0], 16);                                \
    __builtin_memcpy(&af[1], &As[P][ra1], 16);                                \
    __builtin_memcpy(&af[2], &As[P][ra2], 16);                                \
    __builtin_memcpy(&af[3], &As[P][ra3], 16);                                \
    __builtin_memcpy(&bfr[0], &Bs[P][rb0], 16);                               \
    __builtin_memcpy(&bfr[1], &Bs[P][rb1], 16);                               \
    __builtin_memcpy(&bfr[2], &Bs[P][rb2], 16);                               \
    __builtin_memcpy(&bfr[3], &Bs[P][rb3], 16);                               \
    _Pragma("unroll")                                                         \
    for (int i = 0; i < 4; ++i)                                               \
      _Pragma("unroll")                                                       \
      for (int j = 0; j < 4; ++j)                                             \
        acc[i][j] = MFMA16(af[i], bfr[j], acc[i][j]);                         \
  } while (0)

  ISSUE(0);
  STAGE(0);
  __syncthreads();

#pragma clang loop unroll(disable)
  for (int kt = 0; kt < 127; ++kt) {
    const int p = kt & 1;
    ISSUE(kt + 1);
    COMPUTE(p);
    STAGE(p ^ 1);
    __syncthreads();
  }
  COMPUTE(1);

#undef ISSUE
#undef STAGE
#undef COMPUTE

  const int cr = (lane >> 4) << 2;
  const int cc = lane & 15;
#pragma unroll
  for (int j = 0; j < 4; ++j) {
    const int n = n0 + wn + j * 16 + cc;
    const float bv = bias[n];
#pragma unroll
    for (int i = 0; i < 4; ++i) {
      const int mrow = m0 + wm + i * 16 + cr;
#pragma unroll
      for (int r = 0; r < 4; ++r)
        out[(size_t)(mrow + r) * NDIM + n] = acc[i][j][r] + bv;
    }
  }
}

extern "C" void kernel_launch(void* const* d_in, const int* in_sizes, int n_in,
                              void* d_out, int out_size, void* d_ws, size_t ws_size,
                              hipStream_t stream) {
  const float* A      = (const float*)d_in[0];
  const int*   qwp    = (const int*)d_in[1];
  const float* scales = (const float*)d_in[2];
  const float* zerosp = (const float*)d_in[3];
  const float* biasp  = (const float*)d_in[4];
  float*       outp   = (float*)d_out;

  const size_t needA = (size_t)MDIM * KDIM * sizeof(_Float16);   // 16 MB

  if (ws_size >= needA) {
    _Float16* Af = (_Float16*)d_ws;
    conv_a_kernel<<<2048, 256, 0, stream>>>(A, Af);
    dim3 grid(NDIM / 256, MDIM / 256);  // 32 x 8 = 256 blocks (1/CU)
    gemm_q_kernel<<<grid, 512, 0, stream>>>(Af, qwp, scales, zerosp, biasp, outp);
  } else {
    dim3 grid(NDIM / 128, MDIM / 128);
    qlin_fused_kernel<<<grid, 256, 0, stream>>>(A, qwp, scales, zerosp, biasp, outp);
  }
}

// Round 21
// 152.182 us; speedup vs baseline: 1.0657x; 1.0117x over previous
//
#include <hip/hip_runtime.h>
#include <stdint.h>

#define MDIM 2048
#define KDIM 4096
#define NDIM 8192
#define NG   32            // K / GROUP_SIZE
#define QROW 2048          // int32 per qweight row
#define NT2  64            // K-tiles of BK=64
#define LSTR 36            // fused-fallback LDS row stride
#define BUFH 32768         // f16 per buffer: A[256][64] + B[256][64]

typedef __attribute__((ext_vector_type(4))) float    f32x4;
typedef __attribute__((ext_vector_type(2))) _Float16 f16x2;
typedef __attribute__((ext_vector_type(8))) _Float16 f16x8;
typedef __attribute__((ext_vector_type(4))) int      i32x4;

#define CVT2(a,b) __builtin_bit_cast(f16x2, __builtin_amdgcn_cvt_pkrtz((a),(b)))
#define BCU(x)    __builtin_bit_cast(unsigned, (x))
#define BCH2(x)   __builtin_bit_cast(f16x2, (x))
#define MFMA16(A,B,C) __builtin_amdgcn_mfma_f32_16x16x32_f16((A),(B),(C),0,0,0)
#define LDSREAD(DST, OFF) __builtin_memcpy(&(DST), &lds[(OFF)], 16)

__device__ __forceinline__ void gload_lds16(const void* g, void* l) {
  __builtin_amdgcn_global_load_lds(
      (const __attribute__((address_space(1))) void*)g,
      (__attribute__((address_space(3))) void*)l, 16, 0, 0);
}

// dequant 4 int32 (8 weights, identity k-order) -> 8 fp16 (verified r3..r20)
__device__ __forceinline__ uint4 dequant8(i32x4 q, float sf, float zf) {
  const _Float16 sh = (_Float16)sf;
  const _Float16 bh = (_Float16)(-zf * sf);
  const f16x2 s2 = {sh, sh}, b2 = {bh, bh};
  const f16x2 k2 = {(_Float16)1024.0f, (_Float16)1024.0f};
  uint4 r;
#define DQE(QV, DST) do {                                                   \
    unsigned Bb_ = (unsigned)(QV) & 0xFFu;                                  \
    unsigned bits_ = ((Bb_ | (Bb_ << 12)) & 0x000F000Fu) | 0x64006400u;     \
    DST = BCU((f16x2)((BCH2(bits_) - k2) * s2 + b2));                       \
  } while (0)
  DQE(q.x, r.x); DQE(q.y, r.y); DQE(q.z, r.z); DQE(q.w, r.w);
#undef DQE
  return r;
}

// ============ pass 1 (merged): W dequant -> Wf f16 AND A f32 -> Af f16 ============
// Item space: [0, 4.19M) = W 8-weight units; [4.19M, 5.24M) = A 8-float units.
// Contiguous ranges -> branch is coherent per block except at one boundary.
__global__ __launch_bounds__(256) void prep_kernel(
    const float* __restrict__ A, const int* __restrict__ qw,
    const float* __restrict__ scales, const float* __restrict__ zeros,
    _Float16* __restrict__ Af, _Float16* __restrict__ Wf)
{
  const size_t wItems = (size_t)NDIM * (KDIM / 8);   // 4,194,304
  const size_t aItems = (size_t)MDIM * (KDIM / 8);   // 1,048,576
  const size_t total  = wItems + aItems;
  for (size_t t = (size_t)blockIdx.x * blockDim.x + threadIdx.x; t < total;
       t += (size_t)gridDim.x * blockDim.x) {
    if (t < wItems) {
      i32x4 q;
      __builtin_memcpy(&q, qw + 4 * t, 16);
      const int n = (int)(t >> 9);            // 512 units per row
      const int k = (int)((t & 511) << 3);
      const int g = k >> 7;
      uint4 w = dequant8(q, scales[n * NG + g], zeros[n * NG + g]);
      __builtin_memcpy(Wf + (size_t)n * KDIM + k, &w, 16);
    } else {
      const size_t u = t - wItems;
      f32x4 v0, v1;
      __builtin_memcpy(&v0, A + 8 * u,     16);
      __builtin_memcpy(&v1, A + 8 * u + 4, 16);
      uint4 h;
      h.x = BCU(CVT2(v0.x, v0.y));
      h.y = BCU(CVT2(v0.z, v0.w));
      h.z = BCU(CVT2(v1.x, v1.y));
      h.w = BCU(CVT2(v1.z, v1.w));
      __builtin_memcpy(Af + 8 * u, &h, 16);
    }
  }
}

// ============ pass 2: f16 GEMM, 256x256, BK=64, 8 waves, free-scheduled phases ============
// r18 VERBATIM (best-measured GEMM: 129.5us, MfmaUtil 47, 0 conflicts):
// 2 x 64KB bufs, staging swizzle schunk=(t&7)^((t>>3)&7), read chunk=
// (kk*4+h)^(fr&7), spread staging 2 gloads/phase, vmcnt(2) gate, 2
// correctness barriers/iter, compiler-scheduled counted lgkmcnt.
__global__ __launch_bounds__(512) void gemm_f16_kernel(
    const _Float16* __restrict__ Af,   // [M][K]
    const _Float16* __restrict__ Wf,   // [N][K]
    const float* __restrict__ bias,    // [N]
    float* __restrict__ out)           // [M][N] f32
{
  __shared__ __align__(16) _Float16 lds[2 * BUFH];   // 128 KB

  const int tid  = threadIdx.x;
  const int wave = tid >> 6;
  const int lane = tid & 63;
  const int n0 = blockIdx.x << 8;
  const int m0 = blockIdx.y << 8;
  const int wm = (wave >> 2) << 7;   // 0 or 128
  const int wn = (wave & 3) << 6;    // 0,64,128,192

  f32x4 acc[8][4] = {};

  // ---- staging (r14-r18 verbatim) ----
  const int srow   = tid >> 3;                      // 0..63
  const int schunk = (tid & 7) ^ ((tid >> 3) & 7);
  const _Float16* aU0 = Af + (size_t)(m0 + srow) * KDIM + schunk * 8;
  const _Float16* aU1 = aU0 + (size_t)64 * KDIM;
  const _Float16* aU2 = aU0 + (size_t)128 * KDIM;
  const _Float16* aU3 = aU0 + (size_t)192 * KDIM;
  const _Float16* bU0 = Wf + (size_t)(n0 + srow) * KDIM + schunk * 8;
  const _Float16* bU1 = bU0 + (size_t)64 * KDIM;
  const _Float16* bU2 = bU0 + (size_t)128 * KDIM;
  const _Float16* bU3 = bU0 + (size_t)192 * KDIM;

#define STAGE_P1(X) do {                                               \
    _Float16* d_ = &lds[((X) & 1) * BUFH + (wave << 9)];               \
    const size_t ko_ = (size_t)(X) << 6;                               \
    gload_lds16(aU0 + ko_, d_);                                        \
    gload_lds16(aU1 + ko_, d_ + 4096);                                 \
  } while (0)
#define STAGE_P2(X) do {                                               \
    _Float16* d_ = &lds[((X) & 1) * BUFH + (wave << 9)];               \
    const size_t ko_ = (size_t)(X) << 6;                               \
    gload_lds16(aU2 + ko_, d_ + 8192);                                 \
    gload_lds16(aU3 + ko_, d_ + 12288);                                \
  } while (0)
#define STAGE_P3(X) do {                                               \
    _Float16* d_ = &lds[((X) & 1) * BUFH + (wave << 9)];               \
    const size_t ko_ = (size_t)(X) << 6;                               \
    gload_lds16(bU0 + ko_, d_ + 16384);                                \
    gload_lds16(bU1 + ko_, d_ + 20480);                                \
  } while (0)
#define STAGE_P4(X) do {                                               \
    _Float16* d_ = &lds[((X) & 1) * BUFH + (wave << 9)];               \
    const size_t ko_ = (size_t)(X) << 6;                               \
    gload_lds16(bU2 + ko_, d_ + 24576);                                \
    gload_lds16(bU3 + ko_, d_ + 28672);                                \
  } while (0)

  // ---- fragment read offsets (measured 0 conflicts r14-r18) ----
  const int fr = lane & 15;
  const int h4 = lane >> 4;
  const int ck0 = (((0 + h4) ^ (fr & 7))) << 3;
  const int ck1 = (((4 + h4) ^ (fr & 7))) << 3;
  int raOff[8], rbOff[4];
#pragma unroll
  for (int i = 0; i < 8; ++i) raOff[i] = (wm + 16 * i + fr) * 64;
#pragma unroll
  for (int j = 0; j < 4; ++j) rbOff[j] = 16384 + (wn + 16 * j + fr) * 64;

  // tail compute (no staging)
#define COMPUTE(T) do {                                                \
    const int bb_ = ((T) & 1) * BUFH;                                  \
    f16x8 b0_[4], b1_[4];                                              \
    _Pragma("unroll")                                                  \
    for (int j = 0; j < 4; ++j) {                                      \
      LDSREAD(b0_[j], bb_ + rbOff[j] + ck0);                           \
      LDSREAD(b1_[j], bb_ + rbOff[j] + ck1);                           \
    }                                                                  \
    _Pragma("unroll")                                                  \
    for (int i = 0; i < 8; ++i) {                                      \
      f16x8 a0_, a1_;                                                  \
      LDSREAD(a0_, bb_ + raOff[i] + ck0);                              \
      LDSREAD(a1_, bb_ + raOff[i] + ck1);                              \
      _Pragma("unroll")                                                \
      for (int j = 0; j < 4; ++j)                                      \
        acc[i][j] = MFMA16(a0_, b0_[j], acc[i][j]);                    \
      _Pragma("unroll")                                                \
      for (int j = 0; j < 4; ++j)                                      \
        acc[i][j] = MFMA16(a1_, b1_[j], acc[i][j]);                    \
    }                                                                  \
  } while (0)

  // 16-MFMA phase body
#define PH_MFMA(R) do {                                                \
    __builtin_amdgcn_s_setprio(1);                                     \
    _Pragma("unroll")                                                  \
    for (int j = 0; j < 4; ++j) {                                      \
      acc[(R)][j]     = MFMA16(aA0, bf0[j], acc[(R)][j]);              \
      acc[(R) + 1][j] = MFMA16(aB0, bf0[j], acc[(R) + 1][j]);          \
    }                                                                  \
    _Pragma("unroll")                                                  \
    for (int j = 0; j < 4; ++j) {                                      \
      acc[(R)][j]     = MFMA16(aA1, bf1[j], acc[(R)][j]);              \
      acc[(R) + 1][j] = MFMA16(aB1, bf1[j], acc[(R) + 1][j]);          \
    }                                                                  \
    __builtin_amdgcn_s_setprio(0);                                     \
  } while (0)

#define RD_A(I)                                                        \
    LDSREAD(aA0, bb + raOff[I] + ck0);                                 \
    LDSREAD(aA1, bb + raOff[I] + ck1);                                 \
    LDSREAD(aB0, bb + raOff[(I) + 1] + ck0);                           \
    LDSREAD(aB1, bb + raOff[(I) + 1] + ck1);

  // prologue: tile 0 fully + tile 1 part 1  (10 loads outstanding)
  STAGE_P1(0); STAGE_P2(0); STAGE_P3(0); STAGE_P4(0);
  STAGE_P1(1);

#pragma clang loop unroll(disable)
  for (int t = 0; t < NT2 - 2; ++t) {
    // CORRECTNESS barrier #1: tile t fully landed, all waves see it
    asm volatile("s_waitcnt vmcnt(2)" ::: "memory");
    __builtin_amdgcn_s_barrier();
    const int bb = (t & 1) * BUFH;

    f16x8 bf0[4], bf1[4], aA0, aA1, aB0, aB1;

    // ---- P0: all B frags + A rows 0,1 | stage t+1 part2 ----
#pragma unroll
    for (int j = 0; j < 4; ++j) {
      LDSREAD(bf0[j], bb + rbOff[j] + ck0);
      LDSREAD(bf1[j], bb + rbOff[j] + ck1);
    }
    RD_A(0)
    STAGE_P2(t + 1);
    PH_MFMA(0);

    // ---- P1: A rows 2,3 | stage t+1 part3 ----
    RD_A(2)
    STAGE_P3(t + 1);
    PH_MFMA(2);

    // ---- P2: A rows 4,5 | stage t+1 part4 ----
    RD_A(4)
    STAGE_P4(t + 1);
    PH_MFMA(4);

    // ---- P3: A rows 6,7 | CORRECTNESS barrier #2 | stage t+2 p1 ----
    RD_A(6)
    __builtin_amdgcn_s_barrier();   // all waves' buf-t reads retired
    STAGE_P1(t + 2);                // overwrites buf t&1 A rows 0-127
    PH_MFMA(6);
  }

  // tail: outstanding = NT2-2 p2,p3,p4 (6, oldest) + NT2-1 p1 (2)
  STAGE_P2(NT2 - 1); STAGE_P3(NT2 - 1); STAGE_P4(NT2 - 1);   // -> 14
  asm volatile("s_waitcnt vmcnt(8)" ::: "memory");            // NT2-2 done
  __builtin_amdgcn_s_barrier();
  COMPUTE(NT2 - 2);
  asm volatile("s_waitcnt vmcnt(0)" ::: "memory");
  __builtin_amdgcn_s_barrier();
  COMPUTE(NT2 - 1);

#undef STAGE_P1
#undef STAGE_P2
#undef STAGE_P3
#undef STAGE_P4
#undef COMPUTE
#undef PH_MFMA
#undef RD_A

  // epilogue: C/D col = lane&15, row = (lane>>4)*4 + reg (r9-r18 verbatim)
  const int cr = (lane >> 4) << 2;
  const int cc = lane & 15;
#pragma unroll
  for (int j = 0; j < 4; ++j) {
    const int n = n0 + wn + j * 16 + cc;
    const float bv = bias[n];
#pragma unroll
    for (int i = 0; i < 8; ++i) {
      const int mrow = m0 + wm + i * 16 + cr;
#pragma unroll
      for (int r = 0; r < 4; ++r)
        out[(size_t)(mrow + r) * NDIM + n] = acc[i][j][r] + bv;
    }
  }
}

// ============ fused fallback (round-6 kernel, verified PASS) ============
__global__ __launch_bounds__(256, 4) void qlin_fused_kernel(
    const float* __restrict__ A, const int* __restrict__ qw,
    const float* __restrict__ scales, const float* __restrict__ zeros,
    const float* __restrict__ bias, float* __restrict__ out)
{
  __shared__ _Float16 As[2][128 * LSTR];
  __shared__ _Float16 Bs[2][128 * LSTR];

  const int tid  = threadIdx.x;
  const int wave = tid >> 6;
  const int lane = tid & 63;
  const int n0 = blockIdx.x << 7;
  const int m0 = blockIdx.y << 7;
  const int wm = (wave >> 1) << 6;
  const int wn = (wave & 1) << 6;

  f32x4 acc[4][4] = {};

  const int r4 = tid >> 2;
  const int c4 = tid & 3;

  const float* aP0 = A + (size_t)(m0 + r4) * KDIM + c4 * 8;
  const float* aP1 = aP0 + (size_t)64 * KDIM;
  const int*   qP0 = qw + (size_t)(n0 + r4) * QROW + c4 * 4;
  const int*   qP1 = qP0 + (size_t)64 * QROW;
  const float* sP0 = scales + (size_t)(n0 + r4) * NG;
  const float* zP0 = zeros  + (size_t)(n0 + r4) * NG;
  const float* sP1 = sP0 + (size_t)64 * NG;
  const float* zP1 = zP0 + (size_t)64 * NG;

  const int aD0 = r4 * LSTR + c4 * 8;
  const int aD1 = (r4 + 64) * LSTR + c4 * 8;

  const int fr = lane & 15;
  const int k0 = (lane >> 4) * 8;
  const int ra0 = (wm +  0 + fr) * LSTR + k0;
  const int ra1 = (wm + 16 + fr) * LSTR + k0;
  const int ra2 = (wm + 32 + fr) * LSTR + k0;
  const int ra3 = (wm + 48 + fr) * LSTR + k0;
  const int rb0 = (wn +  0 + fr) * LSTR + k0;
  const int rb1 = (wn + 16 + fr) * LSTR + k0;
  const int rb2 = (wn + 32 + fr) * LSTR + k0;
  const int rb3 = (wn + 48 + fr) * LSTR + k0;

  f32x4 pa0, pa1, pa2, pa3;
  i32x4 pq0, pq1;
  float psf0, pzf0, psf1, pzf1;

#define ISSUE(KT) do {                                                        \
    __builtin_memcpy(&pa0, aP0 + (size_t)(KT) * 32,     16);                  \
    __builtin_memcpy(&pa1, aP0 + (size_t)(KT) * 32 + 4, 16);                  \
    __builtin_memcpy(&pa2, aP1 + (size_t)(KT) * 32,     16);                  \
    __builtin_memcpy(&pa3, aP1 + (size_t)(KT) * 32 + 4, 16);                  \
    __builtin_memcpy(&pq0, qP0 + (size_t)(KT) * 16, 16);                      \
    __builtin_memcpy(&pq1, qP1 + (size_t)(KT) * 16, 16);                      \
    const int g_ = (KT) >> 2;                                                 \
    psf0 = sP0[g_]; pzf0 = zP0[g_];                                           \
    psf1 = sP1[g_]; pzf1 = zP1[g_];                                           \
  } while (0)

#define STAGE(P) do {                                                         \
    uint4 aw0_;                                                               \
    aw0_.x = BCU(CVT2(pa0.x, pa0.y));                                         \
    aw0_.y = BCU(CVT2(pa0.z, pa0.w));                                         \
    aw0_.z = BCU(CVT2(pa1.x, pa1.y));                                         \
    aw0_.w = BCU(CVT2(pa1.z, pa1.w));                                         \
    __builtin_memcpy(&As[P][aD0], &aw0_, 16);                                 \
    uint4 aw1_;                                                               \
    aw1_.x = BCU(CVT2(pa2.x, pa2.y));                                         \
    aw1_.y = BCU(CVT2(pa2.z, pa2.w));                                         \
    aw1_.z = BCU(CVT2(pa3.x, pa3.y));                                         \
    aw1_.w = BCU(CVT2(pa3.z, pa3.w));                                         \
    __builtin_memcpy(&As[P][aD1], &aw1_, 16);                                 \
    uint4 bw0_ = dequant8(pq0, psf0, pzf0);                                   \
    __builtin_memcpy(&Bs[P][aD0], &bw0_, 16);                                 \
    uint4 bw1_ = dequant8(pq1, psf1, pzf1);                                   \
    __builtin_memcpy(&Bs[P][aD1], &bw1_, 16);                                 \
  } while (0)

#define COMPUTE(P) do {                                                       \
    f16x8 af[4], bfr[4];                                                      \
    __builtin_memcpy(&af[0], &As[P][ra0], 16);                                \
    __builtin_memcpy(&af[1], &As[P][ra1], 16);                                \
    __builtin_memcpy(&af[2], &As[P][ra2], 16);                                \
    __builtin_memcpy(&af[3], &As[P][ra3], 16);                                \
    __builtin_memcpy(&bfr[0], &Bs[P][rb0], 16);                               \
    __builtin_memcpy(&bfr[1], &Bs[P][rb1], 16);                               \
    __builtin_memcpy(&bfr[2], &Bs[P][rb2], 16);                               \
    __builtin_memcpy(&bfr[3], &Bs[P][rb3], 16);                               \
    _Pragma("unroll")                                                         \
    for (int i = 0; i < 4; ++i)                                               \
      _Pragma("unroll")                                                       \
      for (int j = 0; j < 4; ++j)                                             \
        acc[i][j] = MFMA16(af[i], bfr[j], acc[i][j]);                         \
  } while (0)

  ISSUE(0);
  STAGE(0);
  __syncthreads();

#pragma clang loop unroll(disable)
  for (int kt = 0; kt < 127; ++kt) {
    const int p = kt & 1;
    ISSUE(kt + 1);
    COMPUTE(p);
    STAGE(p ^ 1);
    __syncthreads();
  }
  COMPUTE(1);

#undef ISSUE
#undef STAGE
#undef COMPUTE

  const int cr = (lane >> 4) << 2;
  const int cc = lane & 15;
#pragma unroll
  for (int j = 0; j < 4; ++j) {
    const int n = n0 + wn + j * 16 + cc;
    const float bv = bias[n];
#pragma unroll
    for (int i = 0; i < 4; ++i) {
      const int mrow = m0 + wm + i * 16 + cr;
#pragma unroll
      for (int r = 0; r < 4; ++r)
        out[(size_t)(mrow + r) * NDIM + n] = acc[i][j][r] + bv;
    }
  }
}

extern "C" void kernel_launch(void* const* d_in, const int* in_sizes, int n_in,
                              void* d_out, int out_size, void* d_ws, size_t ws_size,
                              hipStream_t stream) {
  const float* A      = (const float*)d_in[0];
  const int*   qwp    = (const int*)d_in[1];
  const float* scales = (const float*)d_in[2];
  const float* zerosp = (const float*)d_in[3];
  const float* biasp  = (const float*)d_in[4];
  float*       outp   = (float*)d_out;

  const size_t needW = (size_t)NDIM * KDIM * sizeof(_Float16);   // 64 MB
  const size_t needA = (size_t)MDIM * KDIM * sizeof(_Float16);   // 16 MB

  if (ws_size >= needW + needA) {
    _Float16* Wf = (_Float16*)d_ws;
    _Float16* Af = (_Float16*)((char*)d_ws + needW);
    prep_kernel<<<2048, 256, 0, stream>>>(A, qwp, scales, zerosp, Af, Wf);
    dim3 grid(NDIM / 256, MDIM / 256);  // 32 x 8 = 256 blocks (1/CU)
    gemm_f16_kernel<<<grid, 512, 0, stream>>>(Af, Wf, biasp, outp);
  } else {
    dim3 grid(NDIM / 128, MDIM / 128);
    qlin_fused_kernel<<<grid, 256, 0, stream>>>(A, qwp, scales, zerosp, biasp, outp);
  }
}

// Round 22
// 147.385 us; speedup vs baseline: 1.1004x; 1.0325x over previous
//
#include <hip/hip_runtime.h>
#include <stdint.h>

#define MDIM 2048
#define KDIM 4096
#define NDIM 8192
#define NG   32            // K / GROUP_SIZE
#define QROW 2048          // int32 per qweight row
#define NT2  64            // K-tiles of BK=64
#define LSTR 36            // fused-fallback LDS row stride
#define BUFH 32768         // elems per buffer: A[256][64] + B[256][64] (16-bit)

typedef __attribute__((ext_vector_type(4))) float    f32x4;
typedef __attribute__((ext_vector_type(2))) _Float16 f16x2;
typedef __attribute__((ext_vector_type(8))) _Float16 f16x8;
typedef __attribute__((ext_vector_type(8))) short    bf16x8;
typedef __attribute__((ext_vector_type(4))) int      i32x4;

#define CVT2(a,b) __builtin_bit_cast(f16x2, __builtin_amdgcn_cvt_pkrtz((a),(b)))
#define BCU(x)    __builtin_bit_cast(unsigned, (x))
#define BCH2(x)   __builtin_bit_cast(f16x2, (x))
#define MFMA16(A,B,C) __builtin_amdgcn_mfma_f32_16x16x32_f16((A),(B),(C),0,0,0)
#define MFMABF(A,B,C) __builtin_amdgcn_mfma_f32_16x16x32_bf16((A),(B),(C),0,0,0)
#define LDSREAD(DST, OFF) __builtin_memcpy(&(DST), &lds[(OFF)], 16)

__device__ __forceinline__ void gload_lds16(const void* g, void* l) {
  __builtin_amdgcn_global_load_lds(
      (const __attribute__((address_space(1))) void*)g,
      (__attribute__((address_space(3))) void*)l, 16, 0, 0);
}

// f32 -> bf16 round-to-nearest-even
__device__ __forceinline__ unsigned bf16rne(float f) {
  unsigned u = __builtin_bit_cast(unsigned, f);
  u += 0x7FFFu + ((u >> 16) & 1u);
  return u >> 16;
}

// dequant 4 int32 (8 weights, identity k-order) -> 8 bf16.
// Exact-f32 path: f32(64+q) = 0x42800000|(q<<17) exact; w = fmaf(f, s, -(64+z)s)
// = (q-z)*s single-rounded, then ONE bf16 rounding (more exact than f16 path).
__device__ __forceinline__ uint4 dequant8_bf(i32x4 q, float sf, float zf) {
  const float b = -(64.0f + zf) * sf;
  uint4 r;
#define DQB(QV, DST) do {                                                     \
    unsigned lo_ = (unsigned)(QV) & 0x0Fu;                                    \
    unsigned hi_ = ((unsigned)(QV) >> 4) & 0x0Fu;                             \
    float w0_ = fmaf(__builtin_bit_cast(float, 0x42800000u | (lo_ << 17)), sf, b); \
    float w1_ = fmaf(__builtin_bit_cast(float, 0x42800000u | (hi_ << 17)), sf, b); \
    DST = bf16rne(w0_) | (bf16rne(w1_) << 16);                                \
  } while (0)
  DQB(q.x, r.x); DQB(q.y, r.y); DQB(q.z, r.z); DQB(q.w, r.w);
#undef DQB
  return r;
}

// f16-path dequant for the fallback kernel (verified r3..r21)
__device__ __forceinline__ uint4 dequant8(i32x4 q, float sf, float zf) {
  const _Float16 sh = (_Float16)sf;
  const _Float16 bh = (_Float16)(-zf * sf);
  const f16x2 s2 = {sh, sh}, b2 = {bh, bh};
  const f16x2 k2 = {(_Float16)1024.0f, (_Float16)1024.0f};
  uint4 r;
#define DQE(QV, DST) do {                                                   \
    unsigned Bb_ = (unsigned)(QV) & 0xFFu;                                  \
    unsigned bits_ = ((Bb_ | (Bb_ << 12)) & 0x000F000Fu) | 0x64006400u;     \
    DST = BCU((f16x2)((BCH2(bits_) - k2) * s2 + b2));                       \
  } while (0)
  DQE(q.x, r.x); DQE(q.y, r.y); DQE(q.z, r.z); DQE(q.w, r.w);
#undef DQE
  return r;
}

// ============ pass 1 (merged): W dequant -> Wf bf16 AND A f32 -> Af bf16 ============
__global__ __launch_bounds__(256) void prep_kernel(
    const float* __restrict__ A, const int* __restrict__ qw,
    const float* __restrict__ scales, const float* __restrict__ zeros,
    unsigned short* __restrict__ Af, unsigned short* __restrict__ Wf)
{
  const size_t wItems = (size_t)NDIM * (KDIM / 8);   // 4,194,304
  const size_t aItems = (size_t)MDIM * (KDIM / 8);   // 1,048,576
  const size_t total  = wItems + aItems;
  for (size_t t = (size_t)blockIdx.x * blockDim.x + threadIdx.x; t < total;
       t += (size_t)gridDim.x * blockDim.x) {
    if (t < wItems) {
      i32x4 q;
      __builtin_memcpy(&q, qw + 4 * t, 16);
      const int n = (int)(t >> 9);            // 512 units per row
      const int k = (int)((t & 511) << 3);
      const int g = k >> 7;
      uint4 w = dequant8_bf(q, scales[n * NG + g], zeros[n * NG + g]);
      __builtin_memcpy(Wf + (size_t)n * KDIM + k, &w, 16);
    } else {
      const size_t u = t - wItems;
      f32x4 v0, v1;
      __builtin_memcpy(&v0, A + 8 * u,     16);
      __builtin_memcpy(&v1, A + 8 * u + 4, 16);
      uint4 h;
      h.x = bf16rne(v0.x) | (bf16rne(v0.y) << 16);
      h.y = bf16rne(v0.z) | (bf16rne(v0.w) << 16);
      h.z = bf16rne(v1.x) | (bf16rne(v1.y) << 16);
      h.w = bf16rne(v1.z) | (bf16rne(v1.w) << 16);
      __builtin_memcpy(Af + 8 * u, &h, 16);
    }
  }
}

// ============ pass 2: bf16 GEMM, 256x256, BK=64, 8 waves, free-scheduled phases ============
// r18/r21 skeleton VERBATIM (best-measured: 129.5us, MfmaUtil 47, 0 conflicts);
// only the MFMA dtype changed f16 -> bf16 (2075 vs 1955 TF measured ceiling).
__global__ __launch_bounds__(512) void gemm_bf16_kernel(
    const unsigned short* __restrict__ Af,   // [M][K] bf16
    const unsigned short* __restrict__ Wf,   // [N][K] bf16
    const float* __restrict__ bias,          // [N]
    float* __restrict__ out)                 // [M][N] f32
{
  __shared__ __align__(16) unsigned short lds[2 * BUFH];   // 128 KB

  const int tid  = threadIdx.x;
  const int wave = tid >> 6;
  const int lane = tid & 63;
  const int n0 = blockIdx.x << 8;
  const int m0 = blockIdx.y << 8;
  const int wm = (wave >> 2) << 7;   // 0 or 128
  const int wn = (wave & 3) << 6;    // 0,64,128,192

  f32x4 acc[8][4] = {};

  // ---- staging (r14-r21 verbatim) ----
  const int srow   = tid >> 3;                      // 0..63
  const int schunk = (tid & 7) ^ ((tid >> 3) & 7);
  const unsigned short* aU0 = Af + (size_t)(m0 + srow) * KDIM + schunk * 8;
  const unsigned short* aU1 = aU0 + (size_t)64 * KDIM;
  const unsigned short* aU2 = aU0 + (size_t)128 * KDIM;
  const unsigned short* aU3 = aU0 + (size_t)192 * KDIM;
  const unsigned short* bU0 = Wf + (size_t)(n0 + srow) * KDIM + schunk * 8;
  const unsigned short* bU1 = bU0 + (size_t)64 * KDIM;
  const unsigned short* bU2 = bU0 + (size_t)128 * KDIM;
  const unsigned short* bU3 = bU0 + (size_t)192 * KDIM;

#define STAGE_P1(X) do {                                               \
    unsigned short* d_ = &lds[((X) & 1) * BUFH + (wave << 9)];         \
    const size_t ko_ = (size_t)(X) << 6;                               \
    gload_lds16(aU0 + ko_, d_);                                        \
    gload_lds16(aU1 + ko_, d_ + 4096);                                 \
  } while (0)
#define STAGE_P2(X) do {                                               \
    unsigned short* d_ = &lds[((X) & 1) * BUFH + (wave << 9)];         \
    const size_t ko_ = (size_t)(X) << 6;                               \
    gload_lds16(aU2 + ko_, d_ + 8192);                                 \
    gload_lds16(aU3 + ko_, d_ + 12288);                                \
  } while (0)
#define STAGE_P3(X) do {                                               \
    unsigned short* d_ = &lds[((X) & 1) * BUFH + (wave << 9)];         \
    const size_t ko_ = (size_t)(X) << 6;                               \
    gload_lds16(bU0 + ko_, d_ + 16384);                                \
    gload_lds16(bU1 + ko_, d_ + 20480);                                \
  } while (0)
#define STAGE_P4(X) do {                                               \
    unsigned short* d_ = &lds[((X) & 1) * BUFH + (wave << 9)];         \
    const size_t ko_ = (size_t)(X) << 6;                               \
    gload_lds16(bU2 + ko_, d_ + 24576);                                \
    gload_lds16(bU3 + ko_, d_ + 28672);                                \
  } while (0)

  // ---- fragment read offsets (measured 0 conflicts r14-r21) ----
  const int fr = lane & 15;
  const int h4 = lane >> 4;
  const int ck0 = (((0 + h4) ^ (fr & 7))) << 3;
  const int ck1 = (((4 + h4) ^ (fr & 7))) << 3;
  int raOff[8], rbOff[4];
#pragma unroll
  for (int i = 0; i < 8; ++i) raOff[i] = (wm + 16 * i + fr) * 64;
#pragma unroll
  for (int j = 0; j < 4; ++j) rbOff[j] = 16384 + (wn + 16 * j + fr) * 64;

  // tail compute (no staging)
#define COMPUTE(T) do {                                                \
    const int bb_ = ((T) & 1) * BUFH;                                  \
    bf16x8 b0_[4], b1_[4];                                             \
    _Pragma("unroll")                                                  \
    for (int j = 0; j < 4; ++j) {                                      \
      LDSREAD(b0_[j], bb_ + rbOff[j] + ck0);                           \
      LDSREAD(b1_[j], bb_ + rbOff[j] + ck1);                           \
    }                                                                  \
    _Pragma("unroll")                                                  \
    for (int i = 0; i < 8; ++i) {                                      \
      bf16x8 a0_, a1_;                                                 \
      LDSREAD(a0_, bb_ + raOff[i] + ck0);                              \
      LDSREAD(a1_, bb_ + raOff[i] + ck1);                              \
      _Pragma("unroll")                                                \
      for (int j = 0; j < 4; ++j)                                      \
        acc[i][j] = MFMABF(a0_, b0_[j], acc[i][j]);                    \
      _Pragma("unroll")                                                \
      for (int j = 0; j < 4; ++j)                                      \
        acc[i][j] = MFMABF(a1_, b1_[j], acc[i][j]);                    \
    }                                                                  \
  } while (0)

  // 16-MFMA phase body
#define PH_MFMA(R) do {                                                \
    __builtin_amdgcn_s_setprio(1);                                     \
    _Pragma("unroll")                                                  \
    for (int j = 0; j < 4; ++j) {                                      \
      acc[(R)][j]     = MFMABF(aA0, bf0[j], acc[(R)][j]);              \
      acc[(R) + 1][j] = MFMABF(aB0, bf0[j], acc[(R) + 1][j]);          \
    }                                                                  \
    _Pragma("unroll")                                                  \
    for (int j = 0; j < 4; ++j) {                                      \
      acc[(R)][j]     = MFMABF(aA1, bf1[j], acc[(R)][j]);              \
      acc[(R) + 1][j] = MFMABF(aB1, bf1[j], acc[(R) + 1][j]);          \
    }                                                                  \
    __builtin_amdgcn_s_setprio(0);                                     \
  } while (0)

#define RD_A(I)                                                        \
    LDSREAD(aA0, bb + raOff[I] + ck0);                                 \
    LDSREAD(aA1, bb + raOff[I] + ck1);                                 \
    LDSREAD(aB0, bb + raOff[(I) + 1] + ck0);                           \
    LDSREAD(aB1, bb + raOff[(I) + 1] + ck1);

  // prologue: tile 0 fully + tile 1 part 1  (10 loads outstanding)
  STAGE_P1(0); STAGE_P2(0); STAGE_P3(0); STAGE_P4(0);
  STAGE_P1(1);

#pragma clang loop unroll(disable)
  for (int t = 0; t < NT2 - 2; ++t) {
    // CORRECTNESS barrier #1: tile t fully landed, all waves see it
    asm volatile("s_waitcnt vmcnt(2)" ::: "memory");
    __builtin_amdgcn_s_barrier();
    const int bb = (t & 1) * BUFH;

    bf16x8 bf0[4], bf1[4], aA0, aA1, aB0, aB1;

    // ---- P0: all B frags + A rows 0,1 | stage t+1 part2 ----
#pragma unroll
    for (int j = 0; j < 4; ++j) {
      LDSREAD(bf0[j], bb + rbOff[j] + ck0);
      LDSREAD(bf1[j], bb + rbOff[j] + ck1);
    }
    RD_A(0)
    STAGE_P2(t + 1);
    PH_MFMA(0);

    // ---- P1: A rows 2,3 | stage t+1 part3 ----
    RD_A(2)
    STAGE_P3(t + 1);
    PH_MFMA(2);

    // ---- P2: A rows 4,5 | stage t+1 part4 ----
    RD_A(4)
    STAGE_P4(t + 1);
    PH_MFMA(4);

    // ---- P3: A rows 6,7 | CORRECTNESS barrier #2 | stage t+2 p1 ----
    RD_A(6)
    __builtin_amdgcn_s_barrier();   // all waves' buf-t reads retired
    STAGE_P1(t + 2);                // overwrites buf t&1 A rows 0-127
    PH_MFMA(6);
  }

  // tail: outstanding = NT2-2 p2,p3,p4 (6, oldest) + NT2-1 p1 (2)
  STAGE_P2(NT2 - 1); STAGE_P3(NT2 - 1); STAGE_P4(NT2 - 1);   // -> 14
  asm volatile("s_waitcnt vmcnt(8)" ::: "memory");            // NT2-2 done
  __builtin_amdgcn_s_barrier();
  COMPUTE(NT2 - 2);
  asm volatile("s_waitcnt vmcnt(0)" ::: "memory");
  __builtin_amdgcn_s_barrier();
  COMPUTE(NT2 - 1);

#undef STAGE_P1
#undef STAGE_P2
#undef STAGE_P3
#undef STAGE_P4
#undef COMPUTE
#undef PH_MFMA
#undef RD_A

  // epilogue: C/D col = lane&15, row = (lane>>4)*4 + reg (dtype-independent)
  const int cr = (lane >> 4) << 2;
  const int cc = lane & 15;
#pragma unroll
  for (int j = 0; j < 4; ++j) {
    const int n = n0 + wn + j * 16 + cc;
    const float bv = bias[n];
#pragma unroll
    for (int i = 0; i < 8; ++i) {
      const int mrow = m0 + wm + i * 16 + cr;
#pragma unroll
      for (int r = 0; r < 4; ++r)
        out[(size_t)(mrow + r) * NDIM + n] = acc[i][j][r] + bv;
    }
  }
}

// ============ fused fallback (round-6 kernel, verified PASS) ============
__global__ __launch_bounds__(256, 4) void qlin_fused_kernel(
    const float* __restrict__ A, const int* __restrict__ qw,
    const float* __restrict__ scales, const float* __restrict__ zeros,
    const float* __restrict__ bias, float* __restrict__ out)
{
  __shared__ _Float16 As[2][128 * LSTR];
  __shared__ _Float16 Bs[2][128 * LSTR];

  const int tid  = threadIdx.x;
  const int wave = tid >> 6;
  const int lane = tid & 63;
  const int n0 = blockIdx.x << 7;
  const int m0 = blockIdx.y << 7;
  const int wm = (wave >> 1) << 6;
  const int wn = (wave & 1) << 6;

  f32x4 acc[4][4] = {};

  const int r4 = tid >> 2;
  const int c4 = tid & 3;

  const float* aP0 = A + (size_t)(m0 + r4) * KDIM + c4 * 8;
  const float* aP1 = aP0 + (size_t)64 * KDIM;
  const int*   qP0 = qw + (size_t)(n0 + r4) * QROW + c4 * 4;
  const int*   qP1 = qP0 + (size_t)64 * QROW;
  const float* sP0 = scales + (size_t)(n0 + r4) * NG;
  const float* zP0 = zeros  + (size_t)(n0 + r4) * NG;
  const float* sP1 = sP0 + (size_t)64 * NG;
  const float* zP1 = zP0 + (size_t)64 * NG;

  const int aD0 = r4 * LSTR + c4 * 8;
  const int aD1 = (r4 + 64) * LSTR + c4 * 8;

  const int fr = lane & 15;
  const int k0 = (lane >> 4) * 8;
  const int ra0 = (wm +  0 + fr) * LSTR + k0;
  const int ra1 = (wm + 16 + fr) * LSTR + k0;
  const int ra2 = (wm + 32 + fr) * LSTR + k0;
  const int ra3 = (wm + 48 + fr) * LSTR + k0;
  const int rb0 = (wn +  0 + fr) * LSTR + k0;
  const int rb1 = (wn + 16 + fr) * LSTR + k0;
  const int rb2 = (wn + 32 + fr) * LSTR + k0;
  const int rb3 = (wn + 48 + fr) * LSTR + k0;

  f32x4 pa0, pa1, pa2, pa3;
  i32x4 pq0, pq1;
  float psf0, pzf0, psf1, pzf1;

#define ISSUE(KT) do {                                                        \
    __builtin_memcpy(&pa0, aP0 + (size_t)(KT) * 32,     16);                  \
    __builtin_memcpy(&pa1, aP0 + (size_t)(KT) * 32 + 4, 16);                  \
    __builtin_memcpy(&pa2, aP1 + (size_t)(KT) * 32,     16);                  \
    __builtin_memcpy(&pa3, aP1 + (size_t)(KT) * 32 + 4, 16);                  \
    __builtin_memcpy(&pq0, qP0 + (size_t)(KT) * 16, 16);                      \
    __builtin_memcpy(&pq1, qP1 + (size_t)(KT) * 16, 16);                      \
    const int g_ = (KT) >> 2;                                                 \
    psf0 = sP0[g_]; pzf0 = zP0[g_];                                           \
    psf1 = sP1[g_]; pzf1 = zP1[g_];                                           \
  } while (0)

#define STAGE(P) do {                                                         \
    uint4 aw0_;                                                               \
    aw0_.x = BCU(CVT2(pa0.x, pa0.y));                                         \
    aw0_.y = BCU(CVT2(pa0.z, pa0.w));                                         \
    aw0_.z = BCU(CVT2(pa1.x, pa1.y));                                         \
    aw0_.w = BCU(CVT2(pa1.z, pa1.w));                                         \
    __builtin_memcpy(&As[P][aD0], &aw0_, 16);                                 \
    uint4 aw1_;                                                               \
    aw1_.x = BCU(CVT2(pa2.x, pa2.y));                                         \
    aw1_.y = BCU(CVT2(pa2.z, pa2.w));                                         \
    aw1_.z = BCU(CVT2(pa3.x, pa3.y));                                         \
    aw1_.w = BCU(CVT2(pa3.z, pa3.w));                                         \
    __builtin_memcpy(&As[P][aD1], &aw1_, 16);                                 \
    uint4 bw0_ = dequant8(pq0, psf0, pzf0);                                   \
    __builtin_memcpy(&Bs[P][aD0], &bw0_, 16);                                 \
    uint4 bw1_ = dequant8(pq1, psf1, pzf1);                                   \
    __builtin_memcpy(&Bs[P][aD1], &bw1_, 16);                                 \
  } while (0)

#define COMPUTE(P) do {                                                       \
    f16x8 af[4], bfr[4];                                                      \
    __builtin_memcpy(&af[0], &As[P][ra0], 16);                                \
    __builtin_memcpy(&af[1], &As[P][ra1], 16);                                \
    __builtin_memcpy(&af[2], &As[P][ra2], 16);                                \
    __builtin_memcpy(&af[3], &As[P][ra3], 16);                                \
    __builtin_memcpy(&bfr[0], &Bs[P][rb0], 16);                               \
    __builtin_memcpy(&bfr[1], &Bs[P][rb1], 16);                               \
    __builtin_memcpy(&bfr[2], &Bs[P][rb2], 16);                               \
    __builtin_memcpy(&bfr[3], &Bs[P][rb3], 16);                               \
    _Pragma("unroll")                                                         \
    for (int i = 0; i < 4; ++i)                                               \
      _Pragma("unroll")                                                       \
      for (int j = 0; j < 4; ++j)                                             \
        acc[i][j] = MFMA16(af[i], bfr[j], acc[i][j]);                         \
  } while (0)

  ISSUE(0);
  STAGE(0);
  __syncthreads();

#pragma clang loop unroll(disable)
  for (int kt = 0; kt < 127; ++kt) {
    const int p = kt & 1;
    ISSUE(kt + 1);
    COMPUTE(p);
    STAGE(p ^ 1);
    __syncthreads();
  }
  COMPUTE(1);

#undef ISSUE
#undef STAGE
#undef COMPUTE

  const int cr = (lane >> 4) << 2;
  const int cc = lane & 15;
#pragma unroll
  for (int j = 0; j < 4; ++j) {
    const int n = n0 + wn + j * 16 + cc;
    const float bv = bias[n];
#pragma unroll
    for (int i = 0; i < 4; ++i) {
      const int mrow = m0 + wm + i * 16 + cr;
#pragma unroll
      for (int r = 0; r < 4; ++r)
        out[(size_t)(mrow + r) * NDIM + n] = acc[i][j][r] + bv;
    }
  }
}

extern "C" void kernel_launch(void* const* d_in, const int* in_sizes, int n_in,
                              void* d_out, int out_size, void* d_ws, size_t ws_size,
                              hipStream_t stream) {
  const float* A      = (const float*)d_in[0];
  const int*   qwp    = (const int*)d_in[1];
  const float* scales = (const float*)d_in[2];
  const float* zerosp = (const float*)d_in[3];
  const float* biasp  = (const float*)d_in[4];
  float*       outp   = (float*)d_out;

  const size_t needW = (size_t)NDIM * KDIM * sizeof(unsigned short);   // 64 MB
  const size_t needA = (size_t)MDIM * KDIM * sizeof(unsigned short);   // 16 MB

  if (ws_size >= needW + needA) {
    unsigned short* Wf = (unsigned short*)d_ws;
    unsigned short* Af = (unsigned short*)((char*)d_ws + needW);
    prep_kernel<<<2048, 256, 0, stream>>>(A, qwp, scales, zerosp, Af, Wf);
    dim3 grid(NDIM / 256, MDIM / 256);  // 32 x 8 = 256 blocks (1/CU)
    gemm_bf16_kernel<<<grid, 512, 0, stream>>>(Af, Wf, biasp, outp);
  } else {
    dim3 grid(NDIM / 128, MDIM / 128);
    qlin_fused_kernel<<<grid, 256, 0, stream>>>(A, qwp, scales, zerosp, biasp, outp);
  }
}